// Round 23
// baseline (1101.930 us; speedup 1.0000x reference)
//
#include <hip/hip_runtime.h>
#include <hip/hip_bf16.h>

// Whisper decoder step: L=6, D=768, H=12, FF=3072, V=51865, A=1500, B=32, S=8
#define HH 12
#define DD 768
#define FFD 3072
#define AAn 1500
#define BBn 32
#define RR 256          // B*S token rows
#define VV 51865
#define MAT (768*768)   // 589824
#define LSTR ((size_t)8 * MAT + 2 * (size_t)DD * FFD)   // wt elements per layer
#define TPAD 1536       // padded audio T

#define OP_BIAS 1
#define OP_GELU 2
#define OP_RES  4
#define OP_BF16 8
#define OP_SCAT 16

typedef float f32x4 __attribute__((ext_vector_type(4)));
typedef short s16x8 __attribute__((ext_vector_type(8)));

__device__ __forceinline__ unsigned short f2bf(float f) {
  union { float f; unsigned int u; } v; v.f = f;
  unsigned int r = (v.u + 0x7fffu + ((v.u >> 16) & 1u)) >> 16;
  return (unsigned short)r;
}
__device__ __forceinline__ float bf2f_lo(unsigned int u) {
  union { unsigned int u; float f; } v; v.u = u << 16; return v.f;
}
__device__ __forceinline__ float bf2f_hi(unsigned int u) {
  union { unsigned int u; float f; } v; v.u = u & 0xffff0000u; return v.f;
}

__device__ __forceinline__ void gld_lds16(const unsigned short* g, unsigned short* l) {
  __builtin_amdgcn_global_load_lds(
      (const __attribute__((address_space(1))) void*)g,
      (__attribute__((address_space(3))) void*)l, 16, 0, 0);
}

// -------- fused embedding + first LayerNorm: x = emb[tok]+pos; hb = LN(x) --------
__global__ __launch_bounds__(256) void embed_ln_k(
    const int* __restrict__ toks, const float* __restrict__ emb,
    const float* __restrict__ pos, const float* __restrict__ w,
    const float* __restrict__ b, float* __restrict__ x,
    unsigned short* __restrict__ out) {
  int r = blockIdx.x;
  int s8 = r & 7;
  int tk = toks[r];
  int t = threadIdx.x;
  float v[3];
  #pragma unroll
  for (int j = 0; j < 3; j++) {
    int c = t + j * 256;
    float nv = emb[(size_t)tk * DD + c] + pos[(size_t)s8 * DD + c];
    x[(size_t)r * DD + c] = nv;
    v[j] = nv;
  }
  float s = v[0] + v[1] + v[2];
  for (int o = 32; o; o >>= 1) s += __shfl_down(s, o);
  __shared__ float red[4], red2[4];
  int wid = t >> 6, lane = t & 63;
  if (!lane) red[wid] = s;
  __syncthreads();
  float mean = (red[0] + red[1] + red[2] + red[3]) * (1.f / DD);
  float d0 = v[0] - mean, d1 = v[1] - mean, d2 = v[2] - mean;
  float s2 = d0 * d0 + d1 * d1 + d2 * d2;
  for (int o = 32; o; o >>= 1) s2 += __shfl_down(s2, o);
  if (!lane) red2[wid] = s2;
  __syncthreads();
  float var = (red2[0] + red2[1] + red2[2] + red2[3]) * (1.f / DD);
  float rstd = rsqrtf(var + 1e-5f);
  out[(size_t)r * DD + t]       = f2bf(d0 * rstd * w[t] + b[t]);
  out[(size_t)r * DD + t + 256] = f2bf(d1 * rstd * w[t + 256] + b[t + 256]);
  out[(size_t)r * DD + t + 512] = f2bf(d2 * rstd * w[t + 512] + b[t + 512]);
}

// ---------------- vectorized f32 -> bf16 convert ----------------
__global__ void cvt_bf16v(const float* __restrict__ src, unsigned short* __restrict__ dst,
                          long long n) {
  long long g = ((long long)blockIdx.x * 256 + threadIdx.x) * 8;
  long long stride = (long long)gridDim.x * 256 * 8;
  for (; g < n; g += stride) {
    union { unsigned short us[8]; s16x8 v; } pk;
    float4 f0 = *(const float4*)(src + g);
    float4 f1 = *(const float4*)(src + g + 4);
    pk.us[0] = f2bf(f0.x); pk.us[1] = f2bf(f0.y); pk.us[2] = f2bf(f0.z); pk.us[3] = f2bf(f0.w);
    pk.us[4] = f2bf(f1.x); pk.us[5] = f2bf(f1.y); pk.us[6] = f2bf(f1.z); pk.us[7] = f2bf(f1.w);
    *(s16x8*)(dst + g) = pk.v;
  }
}

// ---------------- build combined qkv bias ----------------
__global__ void build_biases(const float* __restrict__ bq, const float* __restrict__ bv,
                             float* __restrict__ qkvb) {
  int i = blockIdx.x * 256 + threadIdx.x;
  if (i < 6 * 2304) {
    int l = i / 2304, n = i % 2304;
    qkvb[i] = (n < 768) ? bq[l * 768 + n] : (n < 1536 ? 0.f : bv[l * 768 + (n - 1536)]);
  }
}

// -- fused (templated NP): x += bias + sum(NP partials); out = LN(x) as bf16 --------
template <int NP>
__global__ __launch_bounds__(256) void red_resid_ln(
    const float* __restrict__ part, const float* __restrict__ bias,
    float* __restrict__ x, const float* __restrict__ w,
    const float* __restrict__ b, unsigned short* __restrict__ out) {
  int row = blockIdx.x;
  int t = threadIdx.x;
  float v[3];
  #pragma unroll
  for (int j = 0; j < 3; j++) {
    int c = t + j * 256;
    size_t i = (size_t)row * DD + c;
    float nv = x[i] + bias[c];
    #pragma unroll
    for (int p = 0; p < NP; p++) nv += part[(size_t)p * RR * DD + i];
    x[i] = nv;
    v[j] = nv;
  }
  float s = v[0] + v[1] + v[2];
  for (int o = 32; o; o >>= 1) s += __shfl_down(s, o);
  __shared__ float red[4], red2[4];
  int wid = t >> 6, lane = t & 63;
  if (!lane) red[wid] = s;
  __syncthreads();
  float mean = (red[0] + red[1] + red[2] + red[3]) * (1.f / DD);
  float d0 = v[0] - mean, d1 = v[1] - mean, d2 = v[2] - mean;
  float s2 = d0 * d0 + d1 * d1 + d2 * d2;
  for (int o = 32; o; o >>= 1) s2 += __shfl_down(s2, o);
  if (!lane) red2[wid] = s2;
  __syncthreads();
  float var = (red2[0] + red2[1] + red2[2] + red2[3]) * (1.f / DD);
  float rstd = rsqrtf(var + 1e-5f);
  out[(size_t)row * DD + t]       = f2bf(d0 * rstd * w[t] + b[t]);
  out[(size_t)row * DD + t + 256] = f2bf(d1 * rstd * w[t + 256] + b[t + 256]);
  out[(size_t)row * DD + t + 512] = f2bf(d2 * rstd * w[t + 512] + b[t + 512]);
}

// ---------- vectorized transpose of ALL layer weights -> bf16 (64x64 tiles) -------
struct WPtrs { const float* p[10]; };
__global__ __launch_bounds__(256) void transpose_w(
    WPtrs wp, unsigned short* __restrict__ dst) {
  int l = blockIdx.y;
  int idx = blockIdx.x;
  int zz, ct, rt, R, C;
  if (idx < 1152)      { zz = idx / 144; int t = idx % 144; ct = t % 12; rt = t / 12; R = DD; C = DD; }
  else if (idx < 1728) { zz = 8; int t = idx - 1152; ct = t % 48; rt = t / 48; R = DD; C = FFD; }
  else                 { zz = 9; int t = idx - 1728; rt = t % 48; ct = t / 48; R = FFD; C = DD; }
  const float* W = wp.p[zz] + (size_t)l * ((zz < 8) ? MAT : (size_t)DD * FFD);
  size_t doff = (zz < 8) ? (size_t)zz * MAT
                         : ((zz == 8) ? (size_t)8 * MAT : (size_t)8 * MAT + (size_t)FFD * DD);
  unsigned short* Wt = dst + (size_t)l * LSTR + doff;
  __shared__ unsigned short tile[64][65];
  int r0 = rt * 64, c0 = ct * 64;
  int tid = threadIdx.x;
  int rr = tid >> 3, cc = (tid & 7) * 8;
  #pragma unroll
  for (int j = 0; j < 2; j++) {
    int r = r0 + j * 32 + rr;
    const float* sp = W + (size_t)r * C + c0 + cc;
    float4 f0 = *(const float4*)sp, f1 = *(const float4*)(sp + 4);
    unsigned short* tp = &tile[j * 32 + rr][cc];
    tp[0] = f2bf(f0.x); tp[1] = f2bf(f0.y); tp[2] = f2bf(f0.z); tp[3] = f2bf(f0.w);
    tp[4] = f2bf(f1.x); tp[5] = f2bf(f1.y); tp[6] = f2bf(f1.z); tp[7] = f2bf(f1.w);
  }
  __syncthreads();
  #pragma unroll
  for (int j = 0; j < 2; j++) {
    int c = c0 + j * 32 + rr;       // output row
    union { unsigned short us[8]; s16x8 v; } pk;
    #pragma unroll
    for (int i = 0; i < 8; i++) pk.us[i] = tile[cc + i][j * 32 + rr];
    *(s16x8*)&Wt[(size_t)c * R + r0 + cc] = pk.v;
  }
}

// ---------------- GEMM: C[M][*] = A[M][Klen](bf16) * B[N][Klen]^T ------------------
// BK=64, single-buffered 2-barrier K loop. BF32=1: B staged from f32 src with
// in-register f2bf + XOR-swizzled LDS layout (both write and read swizzled).
// gmap 0: (x=n, y=m, z=batch); 1: (x=batch, y=m, z=n) same-b -> same XCD;
// 2: logits 128-row pair map. BM may be 96 (MREP=3) or 256 (MREP=8).
template <int BM, int BN, int BF32>
__global__ __launch_bounds__(256, 2) void gemm_t(
    const unsigned short* __restrict__ A, const unsigned short* __restrict__ Bt,
    const float* __restrict__ Bf32, int NrowsB,
    void* __restrict__ Cv, const float* __restrict__ bias,
    const float* __restrict__ resid, int Klen, int Kstride, int Nout, int Cld,
    long zsA, long zsB, long zsC, long zsBias, int kz, int gmap, int op) {
  constexpr int WM = BM / 2, WN = BN / 2;
  constexpr int MREP = WM / 16, NREP = WN / 16;
  __shared__ unsigned short As[BM * 64];
  __shared__ unsigned short Bs[BN * 64];
  int bx = blockIdx.x, by = blockIdx.y, bz = blockIdx.z;
  if (gmap == 1) { int t = bx; bx = bz; bz = t; }
  else if (gmap == 2) {
    int id = bx;
    bx = (id >> 4) * 8 + (id & 7);
    by = (id >> 3) & 1;
    bz = 0;
  }
  const int n0 = bx * BN, m0 = by * BM;
  const int z = bz;
  const int kbeg = kz ? z * Klen : 0;
  const int tid = threadIdx.x, w = tid >> 6, l = tid & 63;
  const int wr = w >> 1, wc = w & 1;
  f32x4 acc[MREP][NREP] = {};

  const int rowA = l >> 3;        // 0..7 within an 8-row staging group
  const int colK = (l & 7) * 8;   // 0..56
  const unsigned short* gA =
      A + (size_t)z * zsA + (size_t)(m0 + w * (BM / 4) + rowA) * Kstride + colK + kbeg;
  const unsigned short* gB = nullptr;
  if constexpr (!BF32)
    gB = Bt + (size_t)z * zsB + (size_t)(n0 + w * (BN / 4) + rowA) * Kstride + colK + kbeg;

  for (int k0 = 0; k0 < Klen; k0 += 64) {
    __syncthreads();
    #pragma unroll
    for (int p = 0; p < BM / 32; p++)
      gld_lds16(gA + (size_t)(p * 8) * Kstride + k0, &As[(w * (BM / 4) + p * 8) * 64]);
    if constexpr (!BF32) {
      #pragma unroll
      for (int p = 0; p < BN / 32; p++)
        gld_lds16(gB + (size_t)(p * 8) * Kstride + k0, &Bs[(w * (BN / 4) + p * 8) * 64]);
    } else {
      #pragma unroll
      for (int p = 0; p < BN / 32; p++) {
        int grow = n0 + w * (BN / 4) + p * 8 + rowA;
        float4 f0 = make_float4(0.f, 0.f, 0.f, 0.f), f1 = f0;
        if (grow < NrowsB) {
          const float* srcp = Bf32 + (size_t)grow * Kstride + colK + k0 + kbeg;
          f0 = *(const float4*)srcp;
          f1 = *(const float4*)(srcp + 4);
        }
        union { unsigned short us[8]; s16x8 v; } pk;
        pk.us[0] = f2bf(f0.x); pk.us[1] = f2bf(f0.y);
        pk.us[2] = f2bf(f0.z); pk.us[3] = f2bf(f0.w);
        pk.us[4] = f2bf(f1.x); pk.us[5] = f2bf(f1.y);
        pk.us[6] = f2bf(f1.z); pk.us[7] = f2bf(f1.w);
        int wrow = w * (BN / 4) + p * 8 + rowA;
        int wbyte = ((wrow * 64 + colK) * 2) ^ ((wrow & 7) << 4);
        *(s16x8*)((char*)Bs + wbyte) = pk.v;
      }
    }
    __syncthreads();
    #pragma unroll
    for (int kk = 0; kk < 2; kk++) {
      s16x8 aF[MREP], bF[NREP];
      #pragma unroll
      for (int m = 0; m < MREP; m++)
        aF[m] = *(const s16x8*)&As[(wr * WM + m * 16 + (l & 15)) * 64 + kk * 32 + (l >> 4) * 8];
      #pragma unroll
      for (int n = 0; n < NREP; n++) {
        if constexpr (BF32) {
          int brow = wc * WN + n * 16 + (l & 15);
          int bbyte = ((brow * 64 + kk * 32 + (l >> 4) * 8) * 2) ^ ((brow & 7) << 4);
          bF[n] = *(const s16x8*)((const char*)Bs + bbyte);
        } else {
          bF[n] = *(const s16x8*)&Bs[(wc * WN + n * 16 + (l & 15)) * 64 + kk * 32 + (l >> 4) * 8];
        }
      }
      #pragma unroll
      for (int m = 0; m < MREP; m++)
        #pragma unroll
        for (int n = 0; n < NREP; n++)
          acc[m][n] = __builtin_amdgcn_mfma_f32_16x16x32_bf16(aF[m], bF[n], acc[m][n], 0, 0, 0);
    }
  }

  const float* biasz = (op & OP_BIAS) ? bias + (size_t)z * zsBias : nullptr;
  #pragma unroll
  for (int m = 0; m < MREP; m++) {
    int rr0 = m0 + wr * WM + m * 16 + (l >> 4) * 4;
    #pragma unroll
    for (int n = 0; n < NREP; n++) {
      int c = n0 + wc * WN + n * 16 + (l & 15);
      if (c < Nout) {
        float bval = (op & OP_BIAS) ? biasz[c] : 0.f;
        #pragma unroll
        for (int j = 0; j < 4; j++) {
          int r = rr0 + j;
          float val = acc[m][n][j] + bval;
          if (op & OP_GELU) val = 0.5f * val * (1.f + erff(val * 0.70710678118f));
          if (op & OP_RES)  val += resid[(size_t)r * Cld + c];
          if (op & OP_SCAT) {
            int hh = r >> 3;
            if (hh < HH)
              ((unsigned short*)Cv)[((size_t)hh * 256 + z * 8 + (r & 7)) * 768 + c] = f2bf(val);
          } else if (op & OP_BF16) {
            ((unsigned short*)Cv)[(size_t)z * zsC + (size_t)r * Cld + c] = f2bf(val);
          } else {
            ((float*)Cv)[(size_t)z * zsC + (size_t)r * Cld + c] = val;
          }
        }
      }
    }
  }
}

// ---- PV with NT B-operand, M=96 (pad rows dropped): R[s][e] = sum_t P[s][t]*A[t][e]
__global__ __launch_bounds__(256, 2) void pv_nt(
    const unsigned short* __restrict__ P, const unsigned short* __restrict__ audio_bf,
    unsigned short* __restrict__ Rbf) {
  __shared__ unsigned short As[96 * 64];
  __shared__ unsigned short Bs[64 * 32];
  const int b = blockIdx.x, et = blockIdx.z;
  const int n0 = et * 32;
  const int tid = threadIdx.x, w = tid >> 6, l = tid & 63;
  const int wr = w >> 1, wc = w & 1;
  f32x4 acc[3] = {};

  const int rowA = l >> 3;
  const int colK = (l & 7) * 8;
  const unsigned short* gA =
      P + (size_t)b * 128 * TPAD + (size_t)(w * 24 + rowA) * TPAD + colK;
  const int tloc = w * 16 + (l >> 2);     // 0..63 across the 4 waves
  const int eoff = (l & 3) * 8;
  const unsigned short* gBbase = audio_bf + (size_t)b * AAn * DD;

  for (int k0 = 0; k0 < TPAD; k0 += 64) {
    __syncthreads();
    #pragma unroll
    for (int p = 0; p < 3; p++)
      gld_lds16(gA + (size_t)(p * 8) * TPAD + k0, &As[(w * 24 + p * 8) * 64]);
    {
      int tg = k0 + tloc;
      if (tg >= AAn) tg = AAn - 1;        // clamped row; P[.][t>=1500]=0 so harmless
      gld_lds16(gBbase + (size_t)tg * DD + n0 + eoff, &Bs[w * 512]);
    }
    __syncthreads();
    #pragma unroll
    for (int kk = 0; kk < 2; kk++) {
      s16x8 aF[3];
      #pragma unroll
      for (int m = 0; m < 3; m++)
        aF[m] = *(const s16x8*)&As[(wr * 48 + m * 16 + (l & 15)) * 64 + kk * 32 + (l >> 4) * 8];
      union { unsigned short us[8]; s16x8 v; } bF;
      #pragma unroll
      for (int i = 0; i < 8; i++)
        bF.us[i] = Bs[(kk * 32 + (l >> 4) * 8 + i) * 32 + wc * 16 + (l & 15)];
      #pragma unroll
      for (int m = 0; m < 3; m++)
        acc[m] = __builtin_amdgcn_mfma_f32_16x16x32_bf16(aF[m], bF.v, acc[m], 0, 0, 0);
    }
  }

  #pragma unroll
  for (int m = 0; m < 3; m++) {
    int rr0 = wr * 48 + m * 16 + (l >> 4) * 4;
    int c = n0 + wc * 16 + (l & 15);
    #pragma unroll
    for (int j = 0; j < 4; j++) {
      int r = rr0 + j;                 // 0..95 -> hh always < 12
      int hh = r >> 3;
      Rbf[((size_t)hh * 256 + b * 8 + (r & 7)) * 768 + c] = f2bf(acc[m][j]);
    }
  }
}

// ---------------- self attention (S=8, causal), q/k/v packed [256][2304] ----------
__global__ __launch_bounds__(64) void self_attn_k(
    const float* __restrict__ qkv, unsigned short* __restrict__ out) {
  int bh = blockIdx.x;
  int b = bh / HH, h = bh % HH;
  __shared__ float qs[8][65], ks[8][65], vs[8][65], ps[8][9];
  int l = threadIdx.x;
  for (int s = 0; s < 8; s++) {
    size_t base = ((size_t)(b * 8 + s)) * 2304 + h * 64 + l;
    qs[s][l] = qkv[base]; ks[s][l] = qkv[base + 768]; vs[s][l] = qkv[base + 1536];
  }
  __syncthreads();
  int s = l >> 3, t = l & 7;
  float sc = 0.f;
  #pragma unroll
  for (int d = 0; d < 64; d++) sc += qs[s][d] * ks[t][d];
  sc *= 0.125f;
  if (t > s) sc = -1e30f;
  float mx = sc;
  for (int o = 4; o; o >>= 1) mx = fmaxf(mx, __shfl_xor(mx, o, 8));
  float e = __expf(sc - mx);
  float sum = e;
  for (int o = 4; o; o >>= 1) sum += __shfl_xor(sum, o, 8);
  ps[s][t] = e / sum;
  __syncthreads();
  for (int s2 = 0; s2 < 8; s2++) {
    float acc = 0.f;
    #pragma unroll
    for (int t2 = 0; t2 < 8; t2++) acc += ps[s2][t2] * vs[t2][l];
    out[((size_t)(b * 8 + s2)) * DD + h * 64 + l] = f2bf(acc);
  }
}

// ---- Q' build from cq split-K partials (NP=6): Q' = 0.125*(sum p + cbq).cWk_h ----
__global__ __launch_bounds__(256) void qprime_k(
    const float* __restrict__ p2, const float* __restrict__ cbq,
    const float* __restrict__ cWk, unsigned short* __restrict__ Qp) {
  int bh = blockIdx.x;              // b*12 + h
  int b = bh / HH, h = bh % HH;
  __shared__ float qs[8][64];
  int tid = threadIdx.x;
  for (int i = tid; i < 512; i += 256) {
    int s = i >> 6, d = i & 63;
    size_t idx = (size_t)(b * 8 + s) * 768 + h * 64 + d;
    float acc = cbq[h * 64 + d];
    #pragma unroll
    for (int p = 0; p < 6; p++) acc += p2[(size_t)p * RR * DD + idx];
    qs[s][d] = acc * 0.125f;
  }
  __syncthreads();
  for (int e = tid; e < 768; e += 256) {
    const float* wr = cWk + (size_t)e * 768 + h * 64;
    float acc[8] = {};
    #pragma unroll 16
    for (int k = 0; k < 64; k++) {
      float wv = wr[k];
      #pragma unroll
      for (int s = 0; s < 8; s++) acc[s] += qs[s][k] * wv;
    }
    #pragma unroll
    for (int s = 0; s < 8; s++)
      Qp[((size_t)b * 128 + h * 8 + s) * 768 + e] = f2bf(acc[s]);
  }
}

// -------- cross softmax: S bf16 [32][96 of 128][1536] -> P bf16 (normalized) -------
__global__ __launch_bounds__(256) void xsoftmax_k(
    const unsigned short* __restrict__ S, unsigned short* __restrict__ P) {
  int bh = blockIdx.x;              // b*12 + h
  int b = bh / HH, h = bh % HH;
  int w = threadIdx.x >> 6, ln = threadIdx.x & 63;
  for (int rr = w; rr < 8; rr += 4) {
    size_t row = (size_t)b * 128 + h * 8 + rr;
    const unsigned int* sr = (const unsigned int*)(S + row * TPAD);
    unsigned int* pr = (unsigned int*)(P + row * TPAD);
    float v[24];
    float mx = -1e30f;
    #pragma unroll
    for (int i = 0; i < 12; i++) {
      unsigned int u = sr[ln + i * 64];
      int t0 = 2 * (ln + i * 64);
      v[2 * i]     = (t0 < AAn)     ? bf2f_lo(u) : -1e30f;
      v[2 * i + 1] = (t0 + 1 < AAn) ? bf2f_hi(u) : -1e30f;
      mx = fmaxf(mx, fmaxf(v[2 * i], v[2 * i + 1]));
    }
    for (int o = 32; o; o >>= 1) mx = fmaxf(mx, __shfl_xor(mx, o));
    float sum = 0.f;
    #pragma unroll
    for (int i = 0; i < 24; i++) { v[i] = __expf(v[i] - mx); sum += v[i]; }
    for (int o = 32; o; o >>= 1) sum += __shfl_xor(sum, o);
    float inv = 1.f / sum;
    #pragma unroll
    for (int i = 0; i < 12; i++) {
      int t0 = 2 * (ln + i * 64);
      unsigned int lo = (t0 < AAn)     ? f2bf(v[2 * i] * inv)     : 0;
      unsigned int hi = (t0 + 1 < AAn) ? f2bf(v[2 * i + 1] * inv) : 0;
      pr[ln + i * 64] = lo | (hi << 16);
    }
  }
}

// ---------------- host ----------------
static inline void* carve(char*& p, size_t bytes) {
  void* r = p;
  p += (bytes + 255) & ~(size_t)255;
  return r;
}

extern "C" void kernel_launch(void* const* d_in, const int* in_sizes, int n_in,
                              void* d_out, int out_size, void* d_ws, size_t ws_size,
                              hipStream_t stream) {
  const int*   tokens = (const int*)d_in[0];
  const float* audio  = (const float*)d_in[1];
  const float* temb   = (const float*)d_in[2];
  const float* pemb   = (const float*)d_in[3];
  const float* aln_w  = (const float*)d_in[4];
  const float* aln_b  = (const float*)d_in[5];
  const float* Wq = (const float*)d_in[6];
  const float* bq = (const float*)d_in[7];
  const float* Wk = (const float*)d_in[8];
  const float* Wv = (const float*)d_in[9];
  const float* bv = (const float*)d_in[10];
  const float* Wo = (const float*)d_in[11];
  const float* bo = (const float*)d_in[12];
  const float* cln_w = (const float*)d_in[13];
  const float* cln_b = (const float*)d_in[14];
  const float* cWq = (const float*)d_in[15];
  const float* cbq = (const float*)d_in[16];
  const float* cWk = (const float*)d_in[17];
  const float* cWv = (const float*)d_in[18];
  const float* cbv = (const float*)d_in[19];
  const float* cWo = (const float*)d_in[20];
  const float* cbo = (const float*)d_in[21];
  const float* mln_w = (const float*)d_in[22];
  const float* mln_b = (const float*)d_in[23];
  const float* W1 = (const float*)d_in[24];
  const float* b1 = (const float*)d_in[25];
  const float* W2 = (const float*)d_in[26];
  const float* b2 = (const float*)d_in[27];
  const float* lnw = (const float*)d_in[28];
  const float* lnb = (const float*)d_in[29];

  char* cur = (char*)d_ws;
  float* x    = (float*)carve(cur, (size_t)RR * DD * 4);
  float* qkv  = (float*)carve(cur, (size_t)RR * 2304 * 4);
  unsigned short* hb    = (unsigned short*)carve(cur, (size_t)RR * DD * 2);
  unsigned short* attnb = (unsigned short*)carve(cur, (size_t)RR * DD * 2);
  unsigned short* ffb   = (unsigned short*)carve(cur, (size_t)RR * FFD * 2);
  unsigned short* wt    = (unsigned short*)carve(cur, LSTR * 6 * 2);
  unsigned short* audio_bf = (unsigned short*)carve(cur, (size_t)BBn * AAn * DD * 2);
  unsigned short* Sb = (unsigned short*)carve(cur, (size_t)BBn * 128 * TPAD * 2);
  unsigned short* Pb  = (unsigned short*)carve(cur, (size_t)BBn * 128 * TPAD * 2);
  unsigned short* Qp  = (unsigned short*)carve(cur, (size_t)BBn * 128 * DD * 2);
  unsigned short* Rbf = (unsigned short*)carve(cur, (size_t)HH * 256 * DD * 2);
  float* qkvb  = (float*)carve(cur, (size_t)6 * 2304 * 4);
  float* mlp2p = (float*)carve(cur, (size_t)8 * RR * DD * 4);

  auto G64 = [&](const unsigned short* A_, const unsigned short* Bt_, void* C_,
                 const float* bias_, const float* res_, int M_, int Np_,
                 int Klen_, int Kstr_, int Nout_, int Cld_, int op_,
                 int Z_ = 1, long zsA_ = 0, long zsB_ = 0, long zsC_ = 0,
                 long zsBias_ = 0, int kz_ = 0) {
    dim3 g(Np_ / 64, M_ / 64, Z_);
    gemm_t<64, 64, 0><<<g, 256, 0, stream>>>(A_, Bt_, nullptr, 0, C_, bias_, res_,
        Klen_, Kstr_, Nout_, Cld_, zsA_, zsB_, zsC_, zsBias_, kz_, 0, op_);
  };
  auto G32 = [&](const unsigned short* A_, const unsigned short* Bt_, void* C_,
                 const float* bias_, const float* res_, int M_, int Np_,
                 int Klen_, int Kstr_, int Nout_, int Cld_, int op_,
                 int Z_ = 1, long zsA_ = 0, long zsB_ = 0, long zsC_ = 0,
                 long zsBias_ = 0, int kz_ = 0) {
    dim3 g(Np_ / 32, M_ / 32, Z_);
    gemm_t<32, 32, 0><<<g, 256, 0, stream>>>(A_, Bt_, nullptr, 0, C_, bias_, res_,
        Klen_, Kstr_, Nout_, Cld_, zsA_, zsB_, zsC_, zsBias_, kz_, 0, op_);
  };

  // fused embed + first LN (layer 0 self-attn)
  embed_ln_k<<<RR, 256, 0, stream>>>(tokens, temb, pemb, aln_w, aln_b, x, hb);
  // audio -> bf16 (temb stays f32; logits stages it directly)
  cvt_bf16v<<<4096, 256, 0, stream>>>(audio, audio_bf, (long long)BBn * AAn * DD);
  build_biases<<<54, 256, 0, stream>>>(bq, bv, qkvb);

  WPtrs wp;
  wp.p[0] = Wq; wp.p[1] = Wk; wp.p[2] = Wv; wp.p[3] = Wo;
  wp.p[4] = cWq; wp.p[5] = cWk; wp.p[6] = cWv; wp.p[7] = cWo;
  wp.p[8] = W1; wp.p[9] = W2;
  transpose_w<<<dim3(2304, 6, 1), 256, 0, stream>>>(wp, wt);

  for (int l = 0; l < 6; l++) {
    size_t vD = (size_t)l * DD;
    size_t vF = (size_t)l * FFD;
    unsigned short* wtl = wt + (size_t)l * LSTR;

    // --- self attention block (hb already holds LN(x)) ---
    G32(hb, wtl, qkv, qkvb + (size_t)l * 2304, nullptr, RR, 2304, DD, DD, 2304, 2304, OP_BIAS);
    self_attn_k<<<BBn * HH, 64, 0, stream>>>(qkv, attnb);
    // o-proj split-K x6 (Klen=128) -> 288 blocks; fused residual+LN(cross)
    G64(attnb, wtl + (size_t)3 * MAT, mlp2p, nullptr, nullptr, RR, DD, 128, DD, DD, DD,
        0, 6, 0, 0, (long)RR * DD, 0, 1);
    red_resid_ln<6><<<RR, 256, 0, stream>>>(mlp2p, bo + vD, x, cln_w + vD, cln_b + vD, hb);

    // --- cross attention block (KV-free formulation) ---
    G64(hb, wtl + (size_t)4 * MAT, mlp2p, nullptr, nullptr, RR, DD, 128, DD, DD, DD,
        0, 6, 0, 0, (long)RR * DD, 0, 1);
    qprime_k<<<BBn * HH, 256, 0, stream>>>(mlp2p, cbq + vD, cWk + (size_t)l * MAT, Qp);
    // scores: per b, S[b] = Qp[b] (96x768, pad rows dropped) @ audio_b^T -> bf16
    {
      dim3 g(BBn, 1, TPAD / 64);
      gemm_t<96, 64, 0><<<g, 256, 0, stream>>>(Qp, audio_bf, nullptr, 0, Sb, nullptr,
          nullptr, DD, DD, TPAD, TPAD, (long)128 * DD, (long)AAn * DD,
          (long)128 * TPAD, 0, 0, 1, OP_BF16);
    }
    xsoftmax_k<<<BBn * HH, 256, 0, stream>>>(Sb, Pb);
    // PV (NT-B, M=96): R = P[b] @ audio_bf[b] -> scatter to Rbf[h][b*8+s][e]
    {
      dim3 g(BBn, 1, DD / 32);
      pv_nt<<<g, 256, 0, stream>>>(Pb, audio_bf, Rbf);
    }
    // O head-proj: 32x32 tiles -> 192 blocks
    G32(Rbf, wtl + (size_t)6 * MAT, attnb, cbv + vD, nullptr, RR, 64, DD, DD, 64, DD,
        OP_BIAS | OP_BF16, HH, (long)256 * DD, (long)64 * DD, 64, 64, 0);
    // co-proj split-K x6; fused residual+LN(mlp)
    G64(attnb, wtl + (size_t)7 * MAT, mlp2p, nullptr, nullptr, RR, DD, 128, DD, DD, DD,
        0, 6, 0, 0, (long)RR * DD, 0, 1);
    red_resid_ln<6><<<RR, 256, 0, stream>>>(mlp2p, cbo + vD, x, mln_w + vD, mln_b + vD, hb);

    // --- MLP block ---
    G32(hb, wtl + (size_t)8 * MAT, ffb, b1 + vF, nullptr, RR, FFD, DD, DD, FFD, FFD,
        OP_BIAS | OP_GELU | OP_BF16);
    // mlp2 split-K x8 (Klen=384) -> 384 blocks
    G64(ffb, wtl + (size_t)8 * MAT + (size_t)DD * FFD, mlp2p, nullptr, nullptr,
        RR, DD, 384, FFD, DD, DD, 0, 8, 0, 0, (long)RR * DD, 0, 1);
    const float* nw = (l < 5) ? (aln_w + (size_t)(l + 1) * DD) : lnw;
    const float* nb = (l < 5) ? (aln_b + (size_t)(l + 1) * DD) : lnb;
    red_resid_ln<8><<<RR, 256, 0, stream>>>(mlp2p, b2 + vD, x, nw, nb, hb);
  }

  // --- logits: BM=256 x BN=32 -> single m-tile; each temb row staged/converted
  // EXACTLY once (159 MB f32 floor). grid = 1621 n-tiles; XOR-swizzled f32 B LDS ---
  {
    dim3 g((VV + 31) / 32, 1, 1);
    gemm_t<256, 32, 1><<<g, 256, 0, stream>>>(hb, nullptr, temb, VV, d_out, nullptr,
        nullptr, DD, DD, VV, VV, 0, 0, 0, 0, 0, 0, 0);
  }
}

// Round 24
// 1097.674 us; speedup vs baseline: 1.0039x; 1.0039x over previous
//
#include <hip/hip_runtime.h>
#include <hip/hip_bf16.h>

// Whisper decoder step: L=6, D=768, H=12, FF=3072, V=51865, A=1500, B=32, S=8
#define HH 12
#define DD 768
#define FFD 3072
#define AAn 1500
#define BBn 32
#define RR 256          // B*S token rows
#define VV 51865
#define MAT (768*768)   // 589824
#define LSTR ((size_t)8 * MAT + 2 * (size_t)DD * FFD)   // wt elements per layer
#define TPAD 1536       // padded audio T

#define OP_BIAS 1
#define OP_GELU 2
#define OP_RES  4
#define OP_BF16 8
#define OP_SCAT 16

typedef float f32x4 __attribute__((ext_vector_type(4)));
typedef short s16x8 __attribute__((ext_vector_type(8)));

__device__ __forceinline__ unsigned short f2bf(float f) {
  union { float f; unsigned int u; } v; v.f = f;
  unsigned int r = (v.u + 0x7fffu + ((v.u >> 16) & 1u)) >> 16;
  return (unsigned short)r;
}
__device__ __forceinline__ float bf2f_lo(unsigned int u) {
  union { unsigned int u; float f; } v; v.u = u << 16; return v.f;
}
__device__ __forceinline__ float bf2f_hi(unsigned int u) {
  union { unsigned int u; float f; } v; v.u = u & 0xffff0000u; return v.f;
}

__device__ __forceinline__ void gld_lds16(const unsigned short* g, unsigned short* l) {
  __builtin_amdgcn_global_load_lds(
      (const __attribute__((address_space(1))) void*)g,
      (__attribute__((address_space(3))) void*)l, 16, 0, 0);
}

// -------- fused embedding + first LayerNorm: x = emb[tok]+pos; hb = LN(x) --------
__global__ __launch_bounds__(256) void embed_ln_k(
    const int* __restrict__ toks, const float* __restrict__ emb,
    const float* __restrict__ pos, const float* __restrict__ w,
    const float* __restrict__ b, float* __restrict__ x,
    unsigned short* __restrict__ out) {
  int r = blockIdx.x;
  int s8 = r & 7;
  int tk = toks[r];
  int t = threadIdx.x;
  float v[3];
  #pragma unroll
  for (int j = 0; j < 3; j++) {
    int c = t + j * 256;
    float nv = emb[(size_t)tk * DD + c] + pos[(size_t)s8 * DD + c];
    x[(size_t)r * DD + c] = nv;
    v[j] = nv;
  }
  float s = v[0] + v[1] + v[2];
  for (int o = 32; o; o >>= 1) s += __shfl_down(s, o);
  __shared__ float red[4], red2[4];
  int wid = t >> 6, lane = t & 63;
  if (!lane) red[wid] = s;
  __syncthreads();
  float mean = (red[0] + red[1] + red[2] + red[3]) * (1.f / DD);
  float d0 = v[0] - mean, d1 = v[1] - mean, d2 = v[2] - mean;
  float s2 = d0 * d0 + d1 * d1 + d2 * d2;
  for (int o = 32; o; o >>= 1) s2 += __shfl_down(s2, o);
  if (!lane) red2[wid] = s2;
  __syncthreads();
  float var = (red2[0] + red2[1] + red2[2] + red2[3]) * (1.f / DD);
  float rstd = rsqrtf(var + 1e-5f);
  out[(size_t)r * DD + t]       = f2bf(d0 * rstd * w[t] + b[t]);
  out[(size_t)r * DD + t + 256] = f2bf(d1 * rstd * w[t + 256] + b[t + 256]);
  out[(size_t)r * DD + t + 512] = f2bf(d2 * rstd * w[t + 512] + b[t + 512]);
}

// ---------------- vectorized f32 -> bf16 convert ----------------
__global__ void cvt_bf16v(const float* __restrict__ src, unsigned short* __restrict__ dst,
                          long long n) {
  long long g = ((long long)blockIdx.x * 256 + threadIdx.x) * 8;
  long long stride = (long long)gridDim.x * 256 * 8;
  for (; g < n; g += stride) {
    union { unsigned short us[8]; s16x8 v; } pk;
    float4 f0 = *(const float4*)(src + g);
    float4 f1 = *(const float4*)(src + g + 4);
    pk.us[0] = f2bf(f0.x); pk.us[1] = f2bf(f0.y); pk.us[2] = f2bf(f0.z); pk.us[3] = f2bf(f0.w);
    pk.us[4] = f2bf(f1.x); pk.us[5] = f2bf(f1.y); pk.us[6] = f2bf(f1.z); pk.us[7] = f2bf(f1.w);
    *(s16x8*)(dst + g) = pk.v;
  }
}

// ---------------- build combined qkv bias ----------------
__global__ void build_biases(const float* __restrict__ bq, const float* __restrict__ bv,
                             float* __restrict__ qkvb) {
  int i = blockIdx.x * 256 + threadIdx.x;
  if (i < 6 * 2304) {
    int l = i / 2304, n = i % 2304;
    qkvb[i] = (n < 768) ? bq[l * 768 + n] : (n < 1536 ? 0.f : bv[l * 768 + (n - 1536)]);
  }
}

// -- fused (templated NP): x += bias + sum(NP partials); out = LN(x) as bf16 --------
template <int NP>
__global__ __launch_bounds__(256) void red_resid_ln(
    const float* __restrict__ part, const float* __restrict__ bias,
    float* __restrict__ x, const float* __restrict__ w,
    const float* __restrict__ b, unsigned short* __restrict__ out) {
  int row = blockIdx.x;
  int t = threadIdx.x;
  float v[3];
  #pragma unroll
  for (int j = 0; j < 3; j++) {
    int c = t + j * 256;
    size_t i = (size_t)row * DD + c;
    float nv = x[i] + bias[c];
    #pragma unroll
    for (int p = 0; p < NP; p++) nv += part[(size_t)p * RR * DD + i];
    x[i] = nv;
    v[j] = nv;
  }
  float s = v[0] + v[1] + v[2];
  for (int o = 32; o; o >>= 1) s += __shfl_down(s, o);
  __shared__ float red[4], red2[4];
  int wid = t >> 6, lane = t & 63;
  if (!lane) red[wid] = s;
  __syncthreads();
  float mean = (red[0] + red[1] + red[2] + red[3]) * (1.f / DD);
  float d0 = v[0] - mean, d1 = v[1] - mean, d2 = v[2] - mean;
  float s2 = d0 * d0 + d1 * d1 + d2 * d2;
  for (int o = 32; o; o >>= 1) s2 += __shfl_down(s2, o);
  if (!lane) red2[wid] = s2;
  __syncthreads();
  float var = (red2[0] + red2[1] + red2[2] + red2[3]) * (1.f / DD);
  float rstd = rsqrtf(var + 1e-5f);
  out[(size_t)row * DD + t]       = f2bf(d0 * rstd * w[t] + b[t]);
  out[(size_t)row * DD + t + 256] = f2bf(d1 * rstd * w[t + 256] + b[t + 256]);
  out[(size_t)row * DD + t + 512] = f2bf(d2 * rstd * w[t + 512] + b[t + 512]);
}

// ---------- vectorized transpose of ALL layer weights -> bf16 (64x64 tiles) -------
struct WPtrs { const float* p[10]; };
__global__ __launch_bounds__(256) void transpose_w(
    WPtrs wp, unsigned short* __restrict__ dst) {
  int l = blockIdx.y;
  int idx = blockIdx.x;
  int zz, ct, rt, R, C;
  if (idx < 1152)      { zz = idx / 144; int t = idx % 144; ct = t % 12; rt = t / 12; R = DD; C = DD; }
  else if (idx < 1728) { zz = 8; int t = idx - 1152; ct = t % 48; rt = t / 48; R = DD; C = FFD; }
  else                 { zz = 9; int t = idx - 1728; rt = t % 48; ct = t / 48; R = FFD; C = DD; }
  const float* W = wp.p[zz] + (size_t)l * ((zz < 8) ? MAT : (size_t)DD * FFD);
  size_t doff = (zz < 8) ? (size_t)zz * MAT
                         : ((zz == 8) ? (size_t)8 * MAT : (size_t)8 * MAT + (size_t)FFD * DD);
  unsigned short* Wt = dst + (size_t)l * LSTR + doff;
  __shared__ unsigned short tile[64][65];
  int r0 = rt * 64, c0 = ct * 64;
  int tid = threadIdx.x;
  int rr = tid >> 3, cc = (tid & 7) * 8;
  #pragma unroll
  for (int j = 0; j < 2; j++) {
    int r = r0 + j * 32 + rr;
    const float* sp = W + (size_t)r * C + c0 + cc;
    float4 f0 = *(const float4*)sp, f1 = *(const float4*)(sp + 4);
    unsigned short* tp = &tile[j * 32 + rr][cc];
    tp[0] = f2bf(f0.x); tp[1] = f2bf(f0.y); tp[2] = f2bf(f0.z); tp[3] = f2bf(f0.w);
    tp[4] = f2bf(f1.x); tp[5] = f2bf(f1.y); tp[6] = f2bf(f1.z); tp[7] = f2bf(f1.w);
  }
  __syncthreads();
  #pragma unroll
  for (int j = 0; j < 2; j++) {
    int c = c0 + j * 32 + rr;       // output row
    union { unsigned short us[8]; s16x8 v; } pk;
    #pragma unroll
    for (int i = 0; i < 8; i++) pk.us[i] = tile[cc + i][j * 32 + rr];
    *(s16x8*)&Wt[(size_t)c * R + r0 + cc] = pk.v;
  }
}

// ---------------- GEMM: C[M][*] = A[M][Klen](bf16) * B[N][Klen]^T ------------------
// BK=64, single-buffered 2-barrier K loop. BF32=1: B staged from f32 src with
// in-register f2bf + XOR-swizzled LDS layout (both write and read swizzled).
// gmap 0: (x=n, y=m, z=batch); 1: (x=batch, y=m, z=n) same-b -> same XCD;
// 2: logits 128-row pair map (ids i,i+8 = the 2 m-tiles of one n-tile, same XCD);
// BM may be 96 (WM=48, MREP=3).
template <int BM, int BN, int BF32>
__global__ __launch_bounds__(256, 2) void gemm_t(
    const unsigned short* __restrict__ A, const unsigned short* __restrict__ Bt,
    const float* __restrict__ Bf32, int NrowsB,
    void* __restrict__ Cv, const float* __restrict__ bias,
    const float* __restrict__ resid, int Klen, int Kstride, int Nout, int Cld,
    long zsA, long zsB, long zsC, long zsBias, int kz, int gmap, int op) {
  constexpr int WM = BM / 2, WN = BN / 2;
  constexpr int MREP = WM / 16, NREP = WN / 16;
  __shared__ unsigned short As[BM * 64];
  __shared__ unsigned short Bs[BN * 64];
  int bx = blockIdx.x, by = blockIdx.y, bz = blockIdx.z;
  if (gmap == 1) { int t = bx; bx = bz; bz = t; }
  else if (gmap == 2) {
    int id = bx;
    bx = (id >> 4) * 8 + (id & 7);
    by = (id >> 3) & 1;
    bz = 0;
  }
  const int n0 = bx * BN, m0 = by * BM;
  const int z = bz;
  const int kbeg = kz ? z * Klen : 0;
  const int tid = threadIdx.x, w = tid >> 6, l = tid & 63;
  const int wr = w >> 1, wc = w & 1;
  f32x4 acc[MREP][NREP] = {};

  const int rowA = l >> 3;        // 0..7 within an 8-row staging group
  const int colK = (l & 7) * 8;   // 0..56
  const unsigned short* gA =
      A + (size_t)z * zsA + (size_t)(m0 + w * (BM / 4) + rowA) * Kstride + colK + kbeg;
  const unsigned short* gB = nullptr;
  if constexpr (!BF32)
    gB = Bt + (size_t)z * zsB + (size_t)(n0 + w * (BN / 4) + rowA) * Kstride + colK + kbeg;

  for (int k0 = 0; k0 < Klen; k0 += 64) {
    __syncthreads();
    #pragma unroll
    for (int p = 0; p < BM / 32; p++)
      gld_lds16(gA + (size_t)(p * 8) * Kstride + k0, &As[(w * (BM / 4) + p * 8) * 64]);
    if constexpr (!BF32) {
      #pragma unroll
      for (int p = 0; p < BN / 32; p++)
        gld_lds16(gB + (size_t)(p * 8) * Kstride + k0, &Bs[(w * (BN / 4) + p * 8) * 64]);
    } else {
      #pragma unroll
      for (int p = 0; p < BN / 32; p++) {
        int grow = n0 + w * (BN / 4) + p * 8 + rowA;
        float4 f0 = make_float4(0.f, 0.f, 0.f, 0.f), f1 = f0;
        if (grow < NrowsB) {
          const float* srcp = Bf32 + (size_t)grow * Kstride + colK + k0 + kbeg;
          f0 = *(const float4*)srcp;
          f1 = *(const float4*)(srcp + 4);
        }
        union { unsigned short us[8]; s16x8 v; } pk;
        pk.us[0] = f2bf(f0.x); pk.us[1] = f2bf(f0.y);
        pk.us[2] = f2bf(f0.z); pk.us[3] = f2bf(f0.w);
        pk.us[4] = f2bf(f1.x); pk.us[5] = f2bf(f1.y);
        pk.us[6] = f2bf(f1.z); pk.us[7] = f2bf(f1.w);
        int wrow = w * (BN / 4) + p * 8 + rowA;
        int wbyte = ((wrow * 64 + colK) * 2) ^ ((wrow & 7) << 4);
        *(s16x8*)((char*)Bs + wbyte) = pk.v;
      }
    }
    __syncthreads();
    #pragma unroll
    for (int kk = 0; kk < 2; kk++) {
      s16x8 aF[MREP], bF[NREP];
      #pragma unroll
      for (int m = 0; m < MREP; m++)
        aF[m] = *(const s16x8*)&As[(wr * WM + m * 16 + (l & 15)) * 64 + kk * 32 + (l >> 4) * 8];
      #pragma unroll
      for (int n = 0; n < NREP; n++) {
        if constexpr (BF32) {
          int brow = wc * WN + n * 16 + (l & 15);
          int bbyte = ((brow * 64 + kk * 32 + (l >> 4) * 8) * 2) ^ ((brow & 7) << 4);
          bF[n] = *(const s16x8*)((const char*)Bs + bbyte);
        } else {
          bF[n] = *(const s16x8*)&Bs[(wc * WN + n * 16 + (l & 15)) * 64 + kk * 32 + (l >> 4) * 8];
        }
      }
      #pragma unroll
      for (int m = 0; m < MREP; m++)
        #pragma unroll
        for (int n = 0; n < NREP; n++)
          acc[m][n] = __builtin_amdgcn_mfma_f32_16x16x32_bf16(aF[m], bF[n], acc[m][n], 0, 0, 0);
    }
  }

  const float* biasz = (op & OP_BIAS) ? bias + (size_t)z * zsBias : nullptr;
  #pragma unroll
  for (int m = 0; m < MREP; m++) {
    int rr0 = m0 + wr * WM + m * 16 + (l >> 4) * 4;
    #pragma unroll
    for (int n = 0; n < NREP; n++) {
      int c = n0 + wc * WN + n * 16 + (l & 15);
      if (c < Nout) {
        float bval = (op & OP_BIAS) ? biasz[c] : 0.f;
        #pragma unroll
        for (int j = 0; j < 4; j++) {
          int r = rr0 + j;
          float val = acc[m][n][j] + bval;
          if (op & OP_GELU) val = 0.5f * val * (1.f + erff(val * 0.70710678118f));
          if (op & OP_RES)  val += resid[(size_t)r * Cld + c];
          if (op & OP_SCAT) {
            int hh = r >> 3;
            if (hh < HH)
              ((unsigned short*)Cv)[((size_t)hh * 256 + z * 8 + (r & 7)) * 768 + c] = f2bf(val);
          } else if (op & OP_BF16) {
            ((unsigned short*)Cv)[(size_t)z * zsC + (size_t)r * Cld + c] = f2bf(val);
          } else {
            ((float*)Cv)[(size_t)z * zsC + (size_t)r * Cld + c] = val;
          }
        }
      }
    }
  }
}

// ---- PV with NT B-operand, M=96 (pad rows dropped): R[s][e] = sum_t P[s][t]*A[t][e]
__global__ __launch_bounds__(256, 2) void pv_nt(
    const unsigned short* __restrict__ P, const unsigned short* __restrict__ audio_bf,
    unsigned short* __restrict__ Rbf) {
  __shared__ unsigned short As[96 * 64];
  __shared__ unsigned short Bs[64 * 32];
  const int b = blockIdx.x, et = blockIdx.z;
  const int n0 = et * 32;
  const int tid = threadIdx.x, w = tid >> 6, l = tid & 63;
  const int wr = w >> 1, wc = w & 1;
  f32x4 acc[3] = {};

  const int rowA = l >> 3;
  const int colK = (l & 7) * 8;
  const unsigned short* gA =
      P + (size_t)b * 128 * TPAD + (size_t)(w * 24 + rowA) * TPAD + colK;
  const int tloc = w * 16 + (l >> 2);     // 0..63 across the 4 waves
  const int eoff = (l & 3) * 8;
  const unsigned short* gBbase = audio_bf + (size_t)b * AAn * DD;

  for (int k0 = 0; k0 < TPAD; k0 += 64) {
    __syncthreads();
    #pragma unroll
    for (int p = 0; p < 3; p++)
      gld_lds16(gA + (size_t)(p * 8) * TPAD + k0, &As[(w * 24 + p * 8) * 64]);
    {
      int tg = k0 + tloc;
      if (tg >= AAn) tg = AAn - 1;        // clamped row; P[.][t>=1500]=0 so harmless
      gld_lds16(gBbase + (size_t)tg * DD + n0 + eoff, &Bs[w * 512]);
    }
    __syncthreads();
    #pragma unroll
    for (int kk = 0; kk < 2; kk++) {
      s16x8 aF[3];
      #pragma unroll
      for (int m = 0; m < 3; m++)
        aF[m] = *(const s16x8*)&As[(wr * 48 + m * 16 + (l & 15)) * 64 + kk * 32 + (l >> 4) * 8];
      union { unsigned short us[8]; s16x8 v; } bF;
      #pragma unroll
      for (int i = 0; i < 8; i++)
        bF.us[i] = Bs[(kk * 32 + (l >> 4) * 8 + i) * 32 + wc * 16 + (l & 15)];
      #pragma unroll
      for (int m = 0; m < 3; m++)
        acc[m] = __builtin_amdgcn_mfma_f32_16x16x32_bf16(aF[m], bF.v, acc[m], 0, 0, 0);
    }
  }

  #pragma unroll
  for (int m = 0; m < 3; m++) {
    int rr0 = wr * 48 + m * 16 + (l >> 4) * 4;
    int c = n0 + wc * 16 + (l & 15);
    #pragma unroll
    for (int j = 0; j < 4; j++) {
      int r = rr0 + j;                 // 0..95 -> hh always < 12
      int hh = r >> 3;
      Rbf[((size_t)hh * 256 + b * 8 + (r & 7)) * 768 + c] = f2bf(acc[m][j]);
    }
  }
}

// ---------------- self attention (S=8, causal), q/k/v packed [256][2304] ----------
__global__ __launch_bounds__(64) void self_attn_k(
    const float* __restrict__ qkv, unsigned short* __restrict__ out) {
  int bh = blockIdx.x;
  int b = bh / HH, h = bh % HH;
  __shared__ float qs[8][65], ks[8][65], vs[8][65], ps[8][9];
  int l = threadIdx.x;
  for (int s = 0; s < 8; s++) {
    size_t base = ((size_t)(b * 8 + s)) * 2304 + h * 64 + l;
    qs[s][l] = qkv[base]; ks[s][l] = qkv[base + 768]; vs[s][l] = qkv[base + 1536];
  }
  __syncthreads();
  int s = l >> 3, t = l & 7;
  float sc = 0.f;
  #pragma unroll
  for (int d = 0; d < 64; d++) sc += qs[s][d] * ks[t][d];
  sc *= 0.125f;
  if (t > s) sc = -1e30f;
  float mx = sc;
  for (int o = 4; o; o >>= 1) mx = fmaxf(mx, __shfl_xor(mx, o, 8));
  float e = __expf(sc - mx);
  float sum = e;
  for (int o = 4; o; o >>= 1) sum += __shfl_xor(sum, o, 8);
  ps[s][t] = e / sum;
  __syncthreads();
  for (int s2 = 0; s2 < 8; s2++) {
    float acc = 0.f;
    #pragma unroll
    for (int t2 = 0; t2 < 8; t2++) acc += ps[s2][t2] * vs[t2][l];
    out[((size_t)(b * 8 + s2)) * DD + h * 64 + l] = f2bf(acc);
  }
}

// ---- Q' build from cq split-K partials (NP=6): Q' = 0.125*(sum p + cbq).cWk_h ----
__global__ __launch_bounds__(256) void qprime_k(
    const float* __restrict__ p2, const float* __restrict__ cbq,
    const float* __restrict__ cWk, unsigned short* __restrict__ Qp) {
  int bh = blockIdx.x;              // b*12 + h
  int b = bh / HH, h = bh % HH;
  __shared__ float qs[8][64];
  int tid = threadIdx.x;
  for (int i = tid; i < 512; i += 256) {
    int s = i >> 6, d = i & 63;
    size_t idx = (size_t)(b * 8 + s) * 768 + h * 64 + d;
    float acc = cbq[h * 64 + d];
    #pragma unroll
    for (int p = 0; p < 6; p++) acc += p2[(size_t)p * RR * DD + idx];
    qs[s][d] = acc * 0.125f;
  }
  __syncthreads();
  for (int e = tid; e < 768; e += 256) {
    const float* wr = cWk + (size_t)e * 768 + h * 64;
    float acc[8] = {};
    #pragma unroll 16
    for (int k = 0; k < 64; k++) {
      float wv = wr[k];
      #pragma unroll
      for (int s = 0; s < 8; s++) acc[s] += qs[s][k] * wv;
    }
    #pragma unroll
    for (int s = 0; s < 8; s++)
      Qp[((size_t)b * 128 + h * 8 + s) * 768 + e] = f2bf(acc[s]);
  }
}

// -------- cross softmax: S bf16 [32][96 of 128][1536] -> P bf16 (normalized) -------
__global__ __launch_bounds__(256) void xsoftmax_k(
    const unsigned short* __restrict__ S, unsigned short* __restrict__ P) {
  int bh = blockIdx.x;              // b*12 + h
  int b = bh / HH, h = bh % HH;
  int w = threadIdx.x >> 6, ln = threadIdx.x & 63;
  for (int rr = w; rr < 8; rr += 4) {
    size_t row = (size_t)b * 128 + h * 8 + rr;
    const unsigned int* sr = (const unsigned int*)(S + row * TPAD);
    unsigned int* pr = (unsigned int*)(P + row * TPAD);
    float v[24];
    float mx = -1e30f;
    #pragma unroll
    for (int i = 0; i < 12; i++) {
      unsigned int u = sr[ln + i * 64];
      int t0 = 2 * (ln + i * 64);
      v[2 * i]     = (t0 < AAn)     ? bf2f_lo(u) : -1e30f;
      v[2 * i + 1] = (t0 + 1 < AAn) ? bf2f_hi(u) : -1e30f;
      mx = fmaxf(mx, fmaxf(v[2 * i], v[2 * i + 1]));
    }
    for (int o = 32; o; o >>= 1) mx = fmaxf(mx, __shfl_xor(mx, o));
    float sum = 0.f;
    #pragma unroll
    for (int i = 0; i < 24; i++) { v[i] = __expf(v[i] - mx); sum += v[i]; }
    for (int o = 32; o; o >>= 1) sum += __shfl_xor(sum, o);
    float inv = 1.f / sum;
    #pragma unroll
    for (int i = 0; i < 12; i++) {
      int t0 = 2 * (ln + i * 64);
      unsigned int lo = (t0 < AAn)     ? f2bf(v[2 * i] * inv)     : 0;
      unsigned int hi = (t0 + 1 < AAn) ? f2bf(v[2 * i + 1] * inv) : 0;
      pr[ln + i * 64] = lo | (hi << 16);
    }
  }
}

// ---------------- host ----------------
static inline void* carve(char*& p, size_t bytes) {
  void* r = p;
  p += (bytes + 255) & ~(size_t)255;
  return r;
}

extern "C" void kernel_launch(void* const* d_in, const int* in_sizes, int n_in,
                              void* d_out, int out_size, void* d_ws, size_t ws_size,
                              hipStream_t stream) {
  const int*   tokens = (const int*)d_in[0];
  const float* audio  = (const float*)d_in[1];
  const float* temb   = (const float*)d_in[2];
  const float* pemb   = (const float*)d_in[3];
  const float* aln_w  = (const float*)d_in[4];
  const float* aln_b  = (const float*)d_in[5];
  const float* Wq = (const float*)d_in[6];
  const float* bq = (const float*)d_in[7];
  const float* Wk = (const float*)d_in[8];
  const float* Wv = (const float*)d_in[9];
  const float* bv = (const float*)d_in[10];
  const float* Wo = (const float*)d_in[11];
  const float* bo = (const float*)d_in[12];
  const float* cln_w = (const float*)d_in[13];
  const float* cln_b = (const float*)d_in[14];
  const float* cWq = (const float*)d_in[15];
  const float* cbq = (const float*)d_in[16];
  const float* cWk = (const float*)d_in[17];
  const float* cWv = (const float*)d_in[18];
  const float* cbv = (const float*)d_in[19];
  const float* cWo = (const float*)d_in[20];
  const float* cbo = (const float*)d_in[21];
  const float* mln_w = (const float*)d_in[22];
  const float* mln_b = (const float*)d_in[23];
  const float* W1 = (const float*)d_in[24];
  const float* b1 = (const float*)d_in[25];
  const float* W2 = (const float*)d_in[26];
  const float* b2 = (const float*)d_in[27];
  const float* lnw = (const float*)d_in[28];
  const float* lnb = (const float*)d_in[29];

  char* cur = (char*)d_ws;
  float* x    = (float*)carve(cur, (size_t)RR * DD * 4);
  float* qkv  = (float*)carve(cur, (size_t)RR * 2304 * 4);
  unsigned short* hb    = (unsigned short*)carve(cur, (size_t)RR * DD * 2);
  unsigned short* attnb = (unsigned short*)carve(cur, (size_t)RR * DD * 2);
  unsigned short* ffb   = (unsigned short*)carve(cur, (size_t)RR * FFD * 2);
  unsigned short* wt    = (unsigned short*)carve(cur, LSTR * 6 * 2);
  unsigned short* audio_bf = (unsigned short*)carve(cur, (size_t)BBn * AAn * DD * 2);
  unsigned short* Sb = (unsigned short*)carve(cur, (size_t)BBn * 128 * TPAD * 2);
  unsigned short* Pb  = (unsigned short*)carve(cur, (size_t)BBn * 128 * TPAD * 2);
  unsigned short* Qp  = (unsigned short*)carve(cur, (size_t)BBn * 128 * DD * 2);
  unsigned short* Rbf = (unsigned short*)carve(cur, (size_t)HH * 256 * DD * 2);
  float* qkvb  = (float*)carve(cur, (size_t)6 * 2304 * 4);
  float* mlp2p = (float*)carve(cur, (size_t)8 * RR * DD * 4);

  auto G64 = [&](const unsigned short* A_, const unsigned short* Bt_, void* C_,
                 const float* bias_, const float* res_, int M_, int Np_,
                 int Klen_, int Kstr_, int Nout_, int Cld_, int op_,
                 int Z_ = 1, long zsA_ = 0, long zsB_ = 0, long zsC_ = 0,
                 long zsBias_ = 0, int kz_ = 0) {
    dim3 g(Np_ / 64, M_ / 64, Z_);
    gemm_t<64, 64, 0><<<g, 256, 0, stream>>>(A_, Bt_, nullptr, 0, C_, bias_, res_,
        Klen_, Kstr_, Nout_, Cld_, zsA_, zsB_, zsC_, zsBias_, kz_, 0, op_);
  };
  auto G32 = [&](const unsigned short* A_, const unsigned short* Bt_, void* C_,
                 const float* bias_, const float* res_, int M_, int Np_,
                 int Klen_, int Kstr_, int Nout_, int Cld_, int op_,
                 int Z_ = 1, long zsA_ = 0, long zsB_ = 0, long zsC_ = 0,
                 long zsBias_ = 0, int kz_ = 0) {
    dim3 g(Np_ / 32, M_ / 32, Z_);
    gemm_t<32, 32, 0><<<g, 256, 0, stream>>>(A_, Bt_, nullptr, 0, C_, bias_, res_,
        Klen_, Kstr_, Nout_, Cld_, zsA_, zsB_, zsC_, zsBias_, kz_, 0, op_);
  };

  // fused embed + first LN (layer 0 self-attn)
  embed_ln_k<<<RR, 256, 0, stream>>>(tokens, temb, pemb, aln_w, aln_b, x, hb);
  // audio -> bf16 (temb stays f32; logits stages it directly)
  cvt_bf16v<<<4096, 256, 0, stream>>>(audio, audio_bf, (long long)BBn * AAn * DD);
  build_biases<<<54, 256, 0, stream>>>(bq, bv, qkvb);

  WPtrs wp;
  wp.p[0] = Wq; wp.p[1] = Wk; wp.p[2] = Wv; wp.p[3] = Wo;
  wp.p[4] = cWq; wp.p[5] = cWk; wp.p[6] = cWv; wp.p[7] = cWo;
  wp.p[8] = W1; wp.p[9] = W2;
  transpose_w<<<dim3(2304, 6, 1), 256, 0, stream>>>(wp, wt);

  for (int l = 0; l < 6; l++) {
    size_t vD = (size_t)l * DD;
    size_t vF = (size_t)l * FFD;
    unsigned short* wtl = wt + (size_t)l * LSTR;

    // --- self attention block (hb already holds LN(x)) ---
    G32(hb, wtl, qkv, qkvb + (size_t)l * 2304, nullptr, RR, 2304, DD, DD, 2304, 2304, OP_BIAS);
    self_attn_k<<<BBn * HH, 64, 0, stream>>>(qkv, attnb);
    // o-proj split-K x6 (Klen=128) -> 288 blocks; fused residual+LN(cross)
    G64(attnb, wtl + (size_t)3 * MAT, mlp2p, nullptr, nullptr, RR, DD, 128, DD, DD, DD,
        0, 6, 0, 0, (long)RR * DD, 0, 1);
    red_resid_ln<6><<<RR, 256, 0, stream>>>(mlp2p, bo + vD, x, cln_w + vD, cln_b + vD, hb);

    // --- cross attention block (KV-free formulation) ---
    G64(hb, wtl + (size_t)4 * MAT, mlp2p, nullptr, nullptr, RR, DD, 128, DD, DD, DD,
        0, 6, 0, 0, (long)RR * DD, 0, 1);
    qprime_k<<<BBn * HH, 256, 0, stream>>>(mlp2p, cbq + vD, cWk + (size_t)l * MAT, Qp);
    // scores: per b, S[b] = Qp[b] (96x768, pad rows dropped) @ audio_b^T -> bf16
    {
      dim3 g(BBn, 1, TPAD / 64);
      gemm_t<96, 64, 0><<<g, 256, 0, stream>>>(Qp, audio_bf, nullptr, 0, Sb, nullptr,
          nullptr, DD, DD, TPAD, TPAD, (long)128 * DD, (long)AAn * DD,
          (long)128 * TPAD, 0, 0, 1, OP_BF16);
    }
    xsoftmax_k<<<BBn * HH, 256, 0, stream>>>(Sb, Pb);
    // PV (NT-B, M=96): R = P[b] @ audio_bf[b] -> scatter to Rbf[h][b*8+s][e]
    {
      dim3 g(BBn, 1, DD / 32);
      pv_nt<<<g, 256, 0, stream>>>(Pb, audio_bf, Rbf);
    }
    // O head-proj: 32x32 tiles -> 192 blocks
    G32(Rbf, wtl + (size_t)6 * MAT, attnb, cbv + vD, nullptr, RR, 64, DD, DD, 64, DD,
        OP_BIAS | OP_BF16, HH, (long)256 * DD, (long)64 * DD, 64, 64, 0);
    // co-proj split-K x6; fused residual+LN(mlp)
    G64(attnb, wtl + (size_t)7 * MAT, mlp2p, nullptr, nullptr, RR, DD, 128, DD, DD, DD,
        0, 6, 0, 0, (long)RR * DD, 0, 1);
    red_resid_ln<6><<<RR, 256, 0, stream>>>(mlp2p, cbo + vD, x, mln_w + vD, mln_b + vD, hb);

    // --- MLP block ---
    G32(hb, wtl + (size_t)8 * MAT, ffb, b1 + vF, nullptr, RR, FFD, DD, DD, FFD, FFD,
        OP_BIAS | OP_GELU | OP_BF16);
    // mlp2 split-K x8 (Klen=384) -> 384 blocks
    G64(ffb, wtl + (size_t)8 * MAT + (size_t)DD * FFD, mlp2p, nullptr, nullptr,
        RR, DD, 384, FFD, DD, DD, 0, 8, 0, 0, (long)RR * DD, 0, 1);
    const float* nw = (l < 5) ? (aln_w + (size_t)(l + 1) * DD) : lnw;
    const float* nb = (l < 5) ? (aln_b + (size_t)(l + 1) * DD) : lnb;
    red_resid_ln<8><<<RR, 256, 0, stream>>>(mlp2p, b2 + vD, x, nw, nb, hb);
  }

  // --- logits: BM=128 x BN=64 tiles, gmap=2 pairing (ids i,i+8 = 2 m-tiles of one
  // n-tile, same XCD) -> 1632 blocks; B staged from raw f32 temb, XOR-swizzled LDS
  // (measured-best logits config: round 22, 90 us) ---
  {
    dim3 g(1632, 1, 1);
    gemm_t<128, 64, 1><<<g, 256, 0, stream>>>(hb, nullptr, temb, VV, d_out, nullptr,
        nullptr, DD, DD, VV, VV, 0, 0, 0, 0, 0, 2, 0);
  }
}